// Round 5
// baseline (241.827 us; speedup 1.0000x reference)
//
#include <hip/hip_runtime.h>
#include <math.h>

#define BB 64
#define TT 577
#define DD 768
#define DENS 519   // int(577*0.9)
#define NSKIP 58
#define NROWS (BB * TT)   // 36928

typedef float vf4 __attribute__((ext_vector_type(4)));

// Order-preserving map: double bits -> u64 (lexicographic == numeric order).
__device__ inline unsigned long long key_of(double z) {
    long long b = __double_as_longlong(z);
    return (b < 0) ? ~(unsigned long long)b
                   : ((unsigned long long)b | 0x8000000000000000ULL);
}
__device__ inline double key_inv(unsigned long long k) {
    long long b = (k >> 63) ? (long long)(k & 0x7fffffffffffffffULL)
                            : ~(long long)k;
    return __longlong_as_double(b);
}

// ---------------------------------------------------------------------------
// K1: keys, 4 rows per wave. Round-4's 1-row/wave version was wave-lifetime
// bound (~800 cyc serial fp64 shfl-reduce tail per single row -> 2.3 TB/s).
// Interleaving 4 independent reduce chains amortizes the serial tail 4x.
// Math per row is identical to the verified baseline (fp64 dot in the same
// lane/element order + same butterfly sum).
// 36928 rows / 4 = 9232 waves = 2308 blocks x 256.
// ---------------------------------------------------------------------------
__global__ __launch_bounds__(256) void k_prob(const float* __restrict__ x,
                                              const float* __restrict__ w,
                                              const float* __restrict__ bias,
                                              unsigned long long* __restrict__ keys) {
    int waveg = (int)((blockIdx.x * blockDim.x + threadIdx.x) >> 6);
    int lane  = threadIdx.x & 63;
    int r0 = waveg * 4;
    if (r0 >= NROWS) return;

    const float4* w4 = (const float4*)w;
    const float4 wv0 = w4[lane];
    const float4 wv1 = w4[lane + 64];
    const float4 wv2 = w4[lane + 128];
    const double bz = (double)bias[0];

    float4 a[4][3];
#pragma unroll
    for (int r = 0; r < 4; ++r) {
        const float4* r4 = (const float4*)(x + (size_t)(r0 + r) * DD);
        a[r][0] = r4[lane];
        a[r][1] = r4[lane + 64];
        a[r][2] = r4[lane + 128];
    }

    double acc[4];
#pragma unroll
    for (int r = 0; r < 4; ++r) {
        double s = (double)a[r][0].x * (double)wv0.x + (double)a[r][0].y * (double)wv0.y
                 + (double)a[r][0].z * (double)wv0.z + (double)a[r][0].w * (double)wv0.w;
        s += (double)a[r][1].x * (double)wv1.x + (double)a[r][1].y * (double)wv1.y
           + (double)a[r][1].z * (double)wv1.z + (double)a[r][1].w * (double)wv1.w;
        s += (double)a[r][2].x * (double)wv2.x + (double)a[r][2].y * (double)wv2.y
           + (double)a[r][2].z * (double)wv2.z + (double)a[r][2].w * (double)wv2.w;
        acc[r] = s;
    }

    // interleaved butterfly: one latency per level covers all 4 rows
#pragma unroll
    for (int off = 32; off; off >>= 1) {
#pragma unroll
        for (int r = 0; r < 4; ++r)
            acc[r] += __shfl_down(acc[r], off, 64);
    }
    if (lane == 0) {
#pragma unroll
        for (int r = 0; r < 4; ++r)
            keys[r0 + r] = key_of(acc[r] + bz);
    }
}

// ---------------------------------------------------------------------------
// K2: per-batch rank + dst map + softmax + summary (unchanged from verified
// round-4 version). 64 blocks x 1024; keys (4.6 KB) in LDS; broadcast-read
// rank; fp64 softmax; 768-thread summary from L3-hot rows.
// ---------------------------------------------------------------------------
__global__ __launch_bounds__(1024) void k_map(const float* __restrict__ x,
                                              const unsigned long long* __restrict__ keysG,
                                              int* __restrict__ dstRow,
                                              float* __restrict__ out) {
    __shared__ unsigned long long key[TT];
    __shared__ int   skipIdx[NSKIP];
    __shared__ float wsh[NSKIP];
    const int b   = blockIdx.x;
    const int tid = threadIdx.x;
    const float* xb = x + (size_t)b * TT * DD;

    if (tid < TT) key[tid] = keysG[b * TT + tid];
    __syncthreads();

    if (tid < TT) {
        const unsigned long long ki = key[tid];
        int rd = 0;
#pragma unroll 8
        for (int j = 0; j < TT; ++j) {
            unsigned long long kj = key[j];
            rd += ((kj > ki) | ((kj == ki) & (j < tid))) ? 1 : 0;
        }
        int dst;
        if (rd < DENS) {
            dst = b * DENS + rd;
        } else {
            int ra = (TT - 1) - rd;      // distinct fp64 keys: exact complement
            dst = BB * DENS + b * NSKIP + ra;
            skipIdx[ra] = tid;
        }
        dstRow[b * TT + tid] = dst;
    }
    __syncthreads();

    if (tid < 64) {
        double pv = -1.0e300;
        if (tid < NSKIP) {
            double z = key_inv(key[skipIdx[tid]]);
            pv = 1.0 / (1.0 + exp(-z));
        }
        double m = pv;
#pragma unroll
        for (int off = 32; off; off >>= 1) {
            double o = __shfl_down(m, off, 64);
            m = (o > m) ? o : m;
        }
        m = __shfl(m, 0, 64);
        double e = (tid < NSKIP) ? exp(pv - m) : 0.0;
        double s = e;
#pragma unroll
        for (int off = 32; off; off >>= 1)
            s += __shfl_down(s, off, 64);
        s = __shfl(s, 0, 64);
        if (tid < NSKIP) wsh[tid] = (float)(e / s);
    }
    __syncthreads();

    if (tid < DD) {
        float acc = 0.f;
#pragma unroll
        for (int k = 0; k < NSKIP; ++k)
            acc += wsh[k] * xb[(size_t)skipIdx[k] * DD + tid];
        out[(size_t)NROWS * DD + (size_t)b * DD + tid] = acc;
    }
}

// ---------------------------------------------------------------------------
// K3: gather-copy, 2 rows per wave for deeper load/store MLP.
// 36928 rows / 2 = 18464 waves = 4616 blocks x 256.
// ---------------------------------------------------------------------------
__global__ __launch_bounds__(256) void k_copy(const float* __restrict__ x,
                                              const int* __restrict__ dstRow,
                                              float* __restrict__ out) {
    int waveg = (int)((blockIdx.x * blockDim.x + threadIdx.x) >> 6);
    int lane  = threadIdx.x & 63;
    int r0 = waveg * 2;
    if (r0 >= NROWS) return;
    int d0 = dstRow[r0];
    int d1 = dstRow[r0 + 1];
    const vf4* s0 = (const vf4*)(x + (size_t)r0 * DD);
    const vf4* s1 = (const vf4*)(x + (size_t)(r0 + 1) * DD);
    vf4* o0 = (vf4*)(out + (size_t)d0 * DD);
    vf4* o1 = (vf4*)(out + (size_t)d1 * DD);
    vf4 v0a = s0[lane], v0b = s0[lane + 64], v0c = s0[lane + 128];
    vf4 v1a = s1[lane], v1b = s1[lane + 64], v1c = s1[lane + 128];
    __builtin_nontemporal_store(v0a, &o0[lane]);
    __builtin_nontemporal_store(v0b, &o0[lane + 64]);
    __builtin_nontemporal_store(v0c, &o0[lane + 128]);
    __builtin_nontemporal_store(v1a, &o1[lane]);
    __builtin_nontemporal_store(v1b, &o1[lane + 64]);
    __builtin_nontemporal_store(v1c, &o1[lane + 128]);
}

extern "C" void kernel_launch(void* const* d_in, const int* in_sizes, int n_in,
                              void* d_out, int out_size, void* d_ws, size_t ws_size,
                              hipStream_t stream) {
    const float* x    = (const float*)d_in[0];
    const float* w    = (const float*)d_in[1];
    const float* bias = (const float*)d_in[2];
    float* out = (float*)d_out;
    char* ws = (char*)d_ws;

    unsigned long long* keys = (unsigned long long*)ws;   // 36928*8 = 295424 B
    int* dstRow = (int*)(ws + 295424);                    // 36928*4 = 147712 B

    k_prob<<<NROWS / 16, 256, 0, stream>>>(x, w, bias, keys);   // 2308 blocks, 4 waves x 4 rows
    k_map<<<BB, 1024, 0, stream>>>(x, keys, dstRow, out);
    k_copy<<<NROWS / 8, 256, 0, stream>>>(x, dstRow, out);      // 4616 blocks, 4 waves x 2 rows
}

// Round 6
// 237.587 us; speedup vs baseline: 1.0178x; 1.0178x over previous
//
#include <hip/hip_runtime.h>
#include <math.h>

#define BB 64
#define TT 577
#define DD 768
#define DENS 519   // int(577*0.9)
#define NSKIP 58
#define NROWS (BB * TT)   // 36928

typedef float vf4 __attribute__((ext_vector_type(4)));

// Order-preserving map: double bits -> u64 (lexicographic == numeric order).
__device__ inline unsigned long long key_of(double z) {
    long long b = __double_as_longlong(z);
    return (b < 0) ? ~(unsigned long long)b
                   : ((unsigned long long)b | 0x8000000000000000ULL);
}
__device__ inline double key_inv(unsigned long long k) {
    long long b = (k >> 63) ? (long long)(k & 0x7fffffffffffffffULL)
                            : ~(long long)k;
    return __longlong_as_double(b);
}

// ---------------------------------------------------------------------------
// K1: keys. One wave per row, fp64 accumulate — byte-identical math to the
// verified round-0 kernel. Full-machine HBM stream of x (113 MB).
// ---------------------------------------------------------------------------
__global__ __launch_bounds__(256) void k_prob(const float* __restrict__ x,
                                              const float* __restrict__ w,
                                              const float* __restrict__ bias,
                                              unsigned long long* __restrict__ keys) {
    int wave = (int)((blockIdx.x * blockDim.x + threadIdx.x) >> 6);
    int lane = threadIdx.x & 63;
    if (wave >= NROWS) return;
    const float4* r4 = (const float4*)(x + (size_t)wave * DD);
    const float4* w4 = (const float4*)w;
    double acc = 0.0;
#pragma unroll
    for (int i = 0; i < 3; ++i) {
        float4 a = r4[lane + 64 * i];
        float4 b = w4[lane + 64 * i];
        acc += (double)a.x * (double)b.x + (double)a.y * (double)b.y
             + (double)a.z * (double)b.z + (double)a.w * (double)b.w;
    }
#pragma unroll
    for (int off = 32; off; off >>= 1)
        acc += __shfl_down(acc, off, 64);
    if (lane == 0) keys[wave] = key_of(acc + (double)bias[0]);
}

// ---------------------------------------------------------------------------
// K2: single dispatch, 64 + 9232 blocks x 256.
//  blocks 0..63   : summary for batch b — keys->LDS, rank in LDS to find the
//                   58 skipped rows, fp64 softmax (same math as verified
//                   k_soft), 256-thread x 3-dim weighted row sum (L3-hot).
//                   Runs concurrently with the copy blocks (read-BW vs
//                   write-BW), replacing the separate k_soft dispatch.
//  blocks 64..9295: fused rank+scatter (round-0 structure, verified best):
//                   wave-per-row scan of L2-hot keys computing rd only
//                   (ra = 576 - rd, complement verified in rounds 3-5),
//                   32-bit xor-reduce, then 3x float4 copy with NT stores.
// ---------------------------------------------------------------------------
__global__ __launch_bounds__(256) void k_scatter(const float* __restrict__ x,
                                                 const unsigned long long* __restrict__ keys,
                                                 float* __restrict__ out) {
    __shared__ unsigned long long key[TT];
    __shared__ int   skipIdx[NSKIP];
    __shared__ float wsh[NSKIP];
    const int blk = blockIdx.x;
    const int tid = threadIdx.x;

    if (blk < BB) {
        // ---- summary block for batch b ----
        const int b = blk;
        const float* xb = x + (size_t)b * TT * DD;
        for (int t = tid; t < TT; t += 256) key[t] = keys[b * TT + t];
        __syncthreads();
        for (int t = tid; t < TT; t += 256) {
            const unsigned long long ki = key[t];
            int rd = 0;
#pragma unroll 8
            for (int j = 0; j < TT; ++j) {
                unsigned long long kj = key[j];
                rd += ((kj > ki) | ((kj == ki) & (j < t))) ? 1 : 0;
            }
            if (rd >= DENS) skipIdx[(TT - 1) - rd] = t;
        }
        __syncthreads();
        if (tid < 64) {
            double pv = -1.0e300;
            if (tid < NSKIP) {
                double z = key_inv(key[skipIdx[tid]]);
                pv = 1.0 / (1.0 + exp(-z));
            }
            double m = pv;
#pragma unroll
            for (int off = 32; off; off >>= 1) {
                double o = __shfl_down(m, off, 64);
                m = (o > m) ? o : m;
            }
            m = __shfl(m, 0, 64);
            double e = (tid < NSKIP) ? exp(pv - m) : 0.0;
            double s = e;
#pragma unroll
            for (int off = 32; off; off >>= 1)
                s += __shfl_down(s, off, 64);
            s = __shfl(s, 0, 64);
            if (tid < NSKIP) wsh[tid] = (float)(e / s);
        }
        __syncthreads();
        float a0 = 0.f, a1 = 0.f, a2 = 0.f;     // dims tid, tid+256, tid+512
#pragma unroll
        for (int k = 0; k < NSKIP; ++k) {
            float wk = wsh[k];
            const float* row = xb + (size_t)skipIdx[k] * DD;
            a0 += wk * row[tid];
            a1 += wk * row[tid + 256];
            a2 += wk * row[tid + 512];
        }
        float* so = out + (size_t)NROWS * DD + (size_t)b * DD;
        so[tid]       = a0;
        so[tid + 256] = a1;
        so[tid + 512] = a2;
    } else {
        // ---- fused rank + scatter copy ----
        int wave = (blk - BB) * 4 + (tid >> 6);
        int lane = tid & 63;
        int b = wave / TT;
        int i = wave - b * TT;
        const unsigned long long* kb = keys + b * TT;
        unsigned long long ki = kb[i];
        int rd = 0;
#pragma unroll
        for (int c = 0; c < 10; ++c) {
            int j = lane + 64 * c;
            if (j < TT) {
                unsigned long long kj = kb[j];
                rd += ((kj > ki) | ((kj == ki) & (j < i))) ? 1 : 0;
            }
        }
#pragma unroll
        for (int off = 32; off; off >>= 1)
            rd += __shfl_xor(rd, off, 64);      // all lanes get the rank

        size_t dst = (rd < DENS)
            ? (size_t)(b * DENS + rd) * DD
            : (size_t)BB * DENS * DD + (size_t)(b * NSKIP + (TT - 1 - rd)) * DD;

        const vf4* s4 = (const vf4*)(x + (size_t)wave * DD);
        vf4* d4 = (vf4*)(out + dst);
#pragma unroll
        for (int c = 0; c < 3; ++c) {
            vf4 v = s4[lane + 64 * c];
            __builtin_nontemporal_store(v, &d4[lane + 64 * c]);
        }
    }
}

extern "C" void kernel_launch(void* const* d_in, const int* in_sizes, int n_in,
                              void* d_out, int out_size, void* d_ws, size_t ws_size,
                              hipStream_t stream) {
    const float* x    = (const float*)d_in[0];
    const float* w    = (const float*)d_in[1];
    const float* bias = (const float*)d_in[2];
    float* out = (float*)d_out;
    unsigned long long* keys = (unsigned long long*)d_ws;   // 36928*8 = 295424 B

    k_prob<<<NROWS / 4, 256, 0, stream>>>(x, w, bias, keys);
    k_scatter<<<BB + NROWS / 4, 256, 0, stream>>>(x, keys, out);
}